// Round 6
// baseline (39.770 us; speedup 1.0000x reference)
//
#include <hip/hip_runtime.h>

#define DIM 64
#define NPB 256           // nodes per bucket
#define NPB_SHIFT 8       // bin = dst >> 8
#define SEGCAP 4096       // pairs per bucket segment (mean fill ~3070, max ~3300)
#define SEG_SHIFT 12      // SEGCAP = 1<<12
#define K2_THREADS 512
#define K2_U 4
#define K2_EPB (K2_THREADS * K2_U)   // 2048 edges per bin-block
#define SRC_BITS 17
#define SRC_MASK ((1u << SRC_BITS) - 1u)

// Kernel 1: 16 threads per node row, float4 loads.
// s[i]   = dot(x[i], W_rel)
// out[i] = dot(x[i], W_root) + b_rel   (full overwrite -> replay-safe)
// Also zeroes the NB global cursors.
__global__ void node_scores_kernel(const float4* __restrict__ x4,
                                   const float4* __restrict__ Wrel4,
                                   const float* __restrict__ b_rel,
                                   const float4* __restrict__ Wroot4,
                                   float* __restrict__ s,
                                   float* __restrict__ out,
                                   int* __restrict__ cursor,
                                   int NB, int n) {
    int gid = blockIdx.x * blockDim.x + threadIdx.x;
    if (gid < NB) cursor[gid] = 0;

    int node = blockIdx.x * 16 + (threadIdx.x >> 4);
    int c = threadIdx.x & 15;
    if (node >= n) return;

    float4 xv = x4[(size_t)node * (DIM / 4) + c];
    float4 wr = Wrel4[c];
    float4 wt = Wroot4[c];
    float sr = xv.x * wr.x + xv.y * wr.y + xv.z * wr.z + xv.w * wr.w;
    float st = xv.x * wt.x + xv.y * wt.y + xv.z * wt.z + xv.w * wt.w;

    #pragma unroll
    for (int off = 1; off < 16; off <<= 1) {
        sr += __shfl_xor(sr, off);
        st += __shfl_xor(st, off);
    }
    if (c == 0) {
        s[node]   = sr;
        out[node] = st + b_rel[0];
    }
}

// Kernel 2: bucket-binning. Histogram 2048 edges over NB bins, exact global
// reservation (one cursor atomic per touched bin), per-wave shfl scans (4
// barriers total), compact packed pairs (dstLocal<<17 | src) bin-ordered in
// LDS, coalesced copy-out.
__global__ __launch_bounds__(K2_THREADS)
void bin_kernel(const int* __restrict__ ei,
                const float* __restrict__ s,
                float* __restrict__ out,
                int* __restrict__ cursor,
                unsigned* __restrict__ bucket,
                int E, int NB) {
    __shared__ unsigned lpair[K2_EPB];  // 8 KB
    __shared__ int  lga[K2_EPB];        // 8 KB
    __shared__ int  hist[K2_THREADS];   // 2 KB (reused as exclusive base)
    __shared__ int  start[K2_THREADS];  // 2 KB (global segment base per bin)
    __shared__ int  wsum[8];

    int tid = threadIdx.x;
    int blk = blockIdx.x;
    hist[tid] = 0;
    __syncthreads();                                   // barrier 1

    int base = blk * K2_EPB + tid * K2_U;
    int dst[K2_U], src[K2_U], rnk[K2_U], bin[K2_U];
    int have = 0;

    if (base + K2_U <= E) {
        const int4* sv = (const int4*)ei;        // src row
        const int4* dv = (const int4*)(ei + E);  // dst row
        int g = base >> 2;
        int4 s0 = sv[g], d0 = dv[g];
        src[0] = s0.x; src[1] = s0.y; src[2] = s0.z; src[3] = s0.w;
        dst[0] = d0.x; dst[1] = d0.y; dst[2] = d0.z; dst[3] = d0.w;
        have = K2_U;
    } else {
        #pragma unroll
        for (int k = 0; k < K2_U; ++k) {
            int e = base + k;
            if (e < E) {
                src[k] = ei[e];
                dst[k] = ei[E + e];
                have = k + 1;
            }
        }
    }

    #pragma unroll
    for (int k = 0; k < K2_U; ++k) {
        if (k < have) {
            bin[k] = dst[k] >> NPB_SHIFT;
            rnk[k] = atomicAdd(&hist[bin[k]], 1);
        }
    }
    __syncthreads();                                   // barrier 2

    int h = hist[tid];
    if (tid < NB && h > 0) start[tid] = atomicAdd(&cursor[tid], h);

    // per-wave inclusive scan of h (no barriers)
    int lane = tid & 63;
    int w = tid >> 6;
    int incl = h;
    #pragma unroll
    for (int off = 1; off < 64; off <<= 1) {
        int v = __shfl_up(incl, off);
        if (lane >= off) incl += v;
    }
    if (lane == 63) wsum[w] = incl;
    __syncthreads();                                   // barrier 3

    int wb = 0;
    #pragma unroll
    for (int i = 0; i < 8; ++i) wb += (i < w) ? wsum[i] : 0;
    hist[tid] = wb + incl - h;       // exclusive base for LDS compaction
    __syncthreads();                                   // barrier 4

    #pragma unroll
    for (int k = 0; k < K2_U; ++k) {
        if (k < have) {
            int b = bin[k];
            int slot = hist[b] + rnk[k];
            int gofs = start[b] + rnk[k];
            if (gofs < SEGCAP) {
                lpair[slot] = ((unsigned)(dst[k] & (NPB - 1)) << SRC_BITS)
                              | (unsigned)src[k];
                lga[slot] = (b << SEG_SHIFT) + gofs;
            } else {                 // statistically never; correctness net
                lga[slot] = -1;
                atomicAdd(&out[dst[k]], s[src[k]]);
            }
        }
    }
    __syncthreads();                                   // barrier 5

    int nE = min(K2_EPB, E - blk * K2_EPB);
    for (int i = tid; i < nE; i += K2_THREADS) {
        int ga = lga[i];
        if (ga >= 0) bucket[ga] = lpair[i];
    }
}

// Kernel 3: one block per bucket. Dense strip read (x4 in flight), gather
// s[src] from L2, LDS accumulate, plain RMW of disjoint out slice.
__global__ __launch_bounds__(NPB)
void gather_kernel(const int* __restrict__ cursor,
                   const unsigned* __restrict__ bucket,
                   const float* __restrict__ s,
                   float* __restrict__ out,
                   int n) {
    __shared__ float acc[NPB];
    int b = blockIdx.x;
    int tid = threadIdx.x;

    acc[tid] = 0.f;
    __syncthreads();

    int total = min(cursor[b], SEGCAP);
    const unsigned* seg = bucket + ((size_t)b << SEG_SHIFT);

    int i = tid;
    for (; i + 3 * NPB < total; i += 4 * NPB) {
        unsigned p0 = seg[i];
        unsigned p1 = seg[i + NPB];
        unsigned p2 = seg[i + 2 * NPB];
        unsigned p3 = seg[i + 3 * NPB];
        float v0 = s[p0 & SRC_MASK];
        float v1 = s[p1 & SRC_MASK];
        float v2 = s[p2 & SRC_MASK];
        float v3 = s[p3 & SRC_MASK];
        atomicAdd(&acc[p0 >> SRC_BITS], v0);
        atomicAdd(&acc[p1 >> SRC_BITS], v1);
        atomicAdd(&acc[p2 >> SRC_BITS], v2);
        atomicAdd(&acc[p3 >> SRC_BITS], v3);
    }
    for (; i < total; i += NPB) {
        unsigned p = seg[i];
        atomicAdd(&acc[p >> SRC_BITS], s[p & SRC_MASK]);
    }
    __syncthreads();

    int g = b * NPB + tid;
    if (g < n) out[g] += acc[tid];
}

extern "C" void kernel_launch(void* const* d_in, const int* in_sizes, int n_in,
                              void* d_out, int out_size, void* d_ws, size_t ws_size,
                              hipStream_t stream) {
    const float* x      = (const float*)d_in[0];
    const int*   ei     = (const int*)d_in[1];
    const float* W_rel  = (const float*)d_in[2];
    const float* b_rel  = (const float*)d_in[3];
    const float* W_root = (const float*)d_in[4];
    float* out = (float*)d_out;

    int n = out_size;                 // N_NODES = 100000
    int E = in_sizes[1] / 2;          // 1200000

    int NB = (n + NPB - 1) / NPB;     // 391 buckets (must be <= K2_THREADS)

    // ws layout: s [n floats] | cursor [NB ints] | bucket [NB*SEGCAP uint]
    float* s = (float*)d_ws;
    size_t off = ((size_t)n * 4 + 255) & ~(size_t)255;
    int* cursor = (int*)((char*)d_ws + off);
    off += ((size_t)NB * 4 + 255) & ~(size_t)255;
    unsigned* bucket = (unsigned*)((char*)d_ws + off);

    // 1) per-node scores + out init + cursor zero
    node_scores_kernel<<<(n + 15) / 16, 256, 0, stream>>>(
        (const float4*)x, (const float4*)W_rel, b_rel, (const float4*)W_root,
        s, out, cursor, NB, n);

    // 2) bin edges into dense packed bucket segments
    int NBLK = (E + K2_EPB - 1) / K2_EPB;   // 586
    bin_kernel<<<NBLK, K2_THREADS, 0, stream>>>(ei, s, out, cursor, bucket, E, NB);

    // 3) per-bucket accumulate + disjoint out RMW
    gather_kernel<<<NB, NPB, 0, stream>>>(cursor, bucket, s, out, n);
}

// Round 7
// 35.809 us; speedup vs baseline: 1.1106x; 1.1106x over previous
//
#include <hip/hip_runtime.h>

#define DIM 64
#define NPB 256           // nodes per bucket
#define NPB_SHIFT 8       // bin = dst >> 8
#define SEGCAP 4096       // pairs per bucket segment (mean ~3072, max ~3300)
#define SEG_SHIFT 12
#define THREADS 512
#define K2_U 8
#define K2_EPB (THREADS * K2_U)      // 4096 edges per bin-block
#define SRC_BITS 17
#define SRC_MASK ((1u << SRC_BITS) - 1u)
#define NODE_ROWS 128     // rows per node-score block (4 rows/thread)
#define OVF_CAP 8192

// Fused kernel: blocks [0,NBLK) bin edges into dense bucket segments;
// blocks [NBLK, NBLK+NODEBLKS) compute per-node scores + out init.
// The two phases are data-independent (binning does not read s).
__global__ __launch_bounds__(THREADS)
void fused_kernel(const float4* __restrict__ x4,
                  const float4* __restrict__ Wrel4,
                  const float* __restrict__ b_rel,
                  const float4* __restrict__ Wroot4,
                  const int* __restrict__ ei,
                  float* __restrict__ s,
                  float* __restrict__ out,
                  int* __restrict__ cursor,      // NB ints, pre-zeroed
                  unsigned* __restrict__ bucket,
                  uint2* __restrict__ ovf,       // overflow list
                  int* __restrict__ ovf_cnt,     // pre-zeroed
                  int E, int NB, int NBLK, int n) {
    __shared__ unsigned lpair[K2_EPB];  // 16 KB
    __shared__ int  lga[K2_EPB];        // 16 KB
    __shared__ int  hist[THREADS];      // 2 KB (reused as exclusive base)
    __shared__ int  start[THREADS];     // 2 KB
    __shared__ int  wsum[8];

    int tid = threadIdx.x;

    if (blockIdx.x < NBLK) {
        // ---------------- binning phase ----------------
        int blk = blockIdx.x;
        hist[tid] = 0;
        __syncthreads();                               // barrier 1

        int base = blk * K2_EPB + tid * K2_U;
        int dst[K2_U], src[K2_U], rnk[K2_U], bin[K2_U];
        int have = 0;

        if (base + K2_U <= E) {
            const int4* sv = (const int4*)ei;          // src row
            const int4* dv = (const int4*)(ei + E);    // dst row
            int g = base >> 2;
            int4 s0 = sv[g], s1 = sv[g + 1];
            int4 d0 = dv[g], d1 = dv[g + 1];
            src[0] = s0.x; src[1] = s0.y; src[2] = s0.z; src[3] = s0.w;
            src[4] = s1.x; src[5] = s1.y; src[6] = s1.z; src[7] = s1.w;
            dst[0] = d0.x; dst[1] = d0.y; dst[2] = d0.z; dst[3] = d0.w;
            dst[4] = d1.x; dst[5] = d1.y; dst[6] = d1.z; dst[7] = d1.w;
            have = K2_U;
        } else {
            #pragma unroll
            for (int k = 0; k < K2_U; ++k) {
                int e = base + k;
                if (e < E) {
                    src[k] = ei[e];
                    dst[k] = ei[E + e];
                    have = k + 1;
                }
            }
        }

        #pragma unroll
        for (int k = 0; k < K2_U; ++k) {
            if (k < have) {
                bin[k] = dst[k] >> NPB_SHIFT;
                rnk[k] = atomicAdd(&hist[bin[k]], 1);
            }
        }
        __syncthreads();                               // barrier 2

        int h = hist[tid];
        if (tid < NB && h > 0) start[tid] = atomicAdd(&cursor[tid], h);

        // per-wave inclusive scan (no barriers)
        int lane = tid & 63;
        int w = tid >> 6;
        int incl = h;
        #pragma unroll
        for (int off = 1; off < 64; off <<= 1) {
            int v = __shfl_up(incl, off);
            if (lane >= off) incl += v;
        }
        if (lane == 63) wsum[w] = incl;
        __syncthreads();                               // barrier 3

        int wb = 0;
        #pragma unroll
        for (int i = 0; i < 8; ++i) wb += (i < w) ? wsum[i] : 0;
        hist[tid] = wb + incl - h;                     // exclusive LDS base
        __syncthreads();                               // barrier 4

        #pragma unroll
        for (int k = 0; k < K2_U; ++k) {
            if (k < have) {
                int b = bin[k];
                int slot = hist[b] + rnk[k];
                int gofs = start[b] + rnk[k];
                if (gofs < SEGCAP) {
                    lpair[slot] = ((unsigned)(dst[k] & (NPB - 1)) << SRC_BITS)
                                  | (unsigned)src[k];
                    lga[slot] = (b << SEG_SHIFT) + gofs;
                } else {   // statistically never; s-free correctness net
                    lga[slot] = -1;
                    int o = atomicAdd(ovf_cnt, 1);
                    if (o < OVF_CAP) ovf[o] = make_uint2((unsigned)dst[k],
                                                         (unsigned)src[k]);
                }
            }
        }
        __syncthreads();                               // barrier 5

        int nE = min(K2_EPB, E - blk * K2_EPB);
        for (int i = tid; i < nE; i += THREADS) {
            int ga = lga[i];
            if (ga >= 0) bucket[ga] = lpair[i];
        }
    } else {
        // ---------------- node-score phase ----------------
        // 16 lanes per row, 4 rows per thread (independent loads in flight).
        int nb = blockIdx.x - NBLK;
        int lane16 = tid & 15;
        int rg = tid >> 4;                  // 0..31
        int rowbase = nb * NODE_ROWS + rg;
        float4 wr = Wrel4[lane16];
        float4 wt = Wroot4[lane16];
        float b0 = b_rel[0];

        float4 xv[4];
        int row[4];
        #pragma unroll
        for (int k = 0; k < 4; ++k) {
            row[k] = rowbase + k * 32;
            xv[k] = (row[k] < n) ? x4[(size_t)row[k] * (DIM / 4) + lane16]
                                 : make_float4(0.f, 0.f, 0.f, 0.f);
        }
        #pragma unroll
        for (int k = 0; k < 4; ++k) {
            float sr = xv[k].x * wr.x + xv[k].y * wr.y
                     + xv[k].z * wr.z + xv[k].w * wr.w;
            float st = xv[k].x * wt.x + xv[k].y * wt.y
                     + xv[k].z * wt.z + xv[k].w * wt.w;
            #pragma unroll
            for (int off = 1; off < 16; off <<= 1) {
                sr += __shfl_xor(sr, off);
                st += __shfl_xor(st, off);
            }
            if (lane16 == 0 && row[k] < n) {
                s[row[k]]   = sr;
                out[row[k]] = st + b0;
            }
        }
    }
}

// Gather: one block per bucket. Dense strip read, L2 gather of s[src],
// LDS accumulate, plain RMW of disjoint out slice. Overflow list (usually
// empty) is filtered per-bucket to stay race-free.
__global__ __launch_bounds__(NPB)
void gather_kernel(const int* __restrict__ cursor,
                   const unsigned* __restrict__ bucket,
                   const float* __restrict__ s,
                   float* __restrict__ out,
                   const uint2* __restrict__ ovf,
                   const int* __restrict__ ovf_cnt,
                   int n) {
    __shared__ float acc[NPB];
    int b = blockIdx.x;
    int tid = threadIdx.x;

    acc[tid] = 0.f;
    __syncthreads();

    int total = min(cursor[b], SEGCAP);
    const unsigned* seg = bucket + ((size_t)b << SEG_SHIFT);

    int i = tid;
    for (; i + 3 * NPB < total; i += 4 * NPB) {
        unsigned p0 = seg[i];
        unsigned p1 = seg[i + NPB];
        unsigned p2 = seg[i + 2 * NPB];
        unsigned p3 = seg[i + 3 * NPB];
        float v0 = s[p0 & SRC_MASK];
        float v1 = s[p1 & SRC_MASK];
        float v2 = s[p2 & SRC_MASK];
        float v3 = s[p3 & SRC_MASK];
        atomicAdd(&acc[p0 >> SRC_BITS], v0);
        atomicAdd(&acc[p1 >> SRC_BITS], v1);
        atomicAdd(&acc[p2 >> SRC_BITS], v2);
        atomicAdd(&acc[p3 >> SRC_BITS], v3);
    }
    for (; i < total; i += NPB) {
        unsigned p = seg[i];
        atomicAdd(&acc[p >> SRC_BITS], s[p & SRC_MASK]);
    }

    int oc = min(*ovf_cnt, OVF_CAP);   // usually 0
    for (int j = tid; j < oc; j += NPB) {
        uint2 p = ovf[j];
        if ((int)(p.x >> NPB_SHIFT) == b)
            atomicAdd(&acc[p.x & (NPB - 1)], s[p.y]);
    }
    __syncthreads();

    int g = b * NPB + tid;
    if (g < n) out[g] += acc[tid];
}

extern "C" void kernel_launch(void* const* d_in, const int* in_sizes, int n_in,
                              void* d_out, int out_size, void* d_ws, size_t ws_size,
                              hipStream_t stream) {
    const float* x      = (const float*)d_in[0];
    const int*   ei     = (const int*)d_in[1];
    const float* W_rel  = (const float*)d_in[2];
    const float* b_rel  = (const float*)d_in[3];
    const float* W_root = (const float*)d_in[4];
    float* out = (float*)d_out;

    int n = out_size;                 // N_NODES = 100000
    int E = in_sizes[1] / 2;          // 1200000

    int NB = (n + NPB - 1) / NPB;     // 391 buckets (<= THREADS required)

    // ws layout: s [n f32] | cursor [NB int] + ovf_cnt [1 int] | ovf | bucket
    float* s = (float*)d_ws;
    size_t off = ((size_t)n * 4 + 255) & ~(size_t)255;
    int* cursor = (int*)((char*)d_ws + off);
    int* ovf_cnt = cursor + NB;
    size_t zero_bytes = (size_t)(NB + 1) * sizeof(int);
    off += (zero_bytes + 255) & ~(size_t)255;
    uint2* ovf = (uint2*)((char*)d_ws + off);
    off += ((size_t)OVF_CAP * sizeof(uint2) + 255) & ~(size_t)255;
    unsigned* bucket = (unsigned*)((char*)d_ws + off);

    // 0) zero cursors + overflow counter (tiny, graph-capture-safe)
    hipMemsetAsync(cursor, 0, zero_bytes, stream);

    // 1) fused: binning blocks first, node-score blocks behind them
    int NBLK = (E + K2_EPB - 1) / K2_EPB;            // 293
    int NODEBLKS = (n + NODE_ROWS - 1) / NODE_ROWS;  // 782
    fused_kernel<<<NBLK + NODEBLKS, THREADS, 0, stream>>>(
        (const float4*)x, (const float4*)W_rel, b_rel, (const float4*)W_root,
        ei, s, out, cursor, bucket, ovf, ovf_cnt, E, NB, NBLK, n);

    // 2) per-bucket accumulate + disjoint out RMW
    gather_kernel<<<NB, NPB, 0, stream>>>(cursor, bucket, s, out, ovf, ovf_cnt, n);
}